// Round 1
// baseline (2552.544 us; speedup 1.0000x reference)
//
#include <hip/hip_runtime.h>

#define BB 1024
#define TT 2048
#define NIN 8
#define NHI 64

// tg replication: jnp.linspace(0, 2e-11*2047*1e9, 2048) in f32
__device__ __forceinline__ float tg_delta() { return 40.94f / 2047.0f; }

// ---------------- precompute r = 1/exp(tau + dparam) for all eval points ----
// layout: r_out[stage][b][s], stage 0 = grid point s (s=0..T-1),
// stage 1 = t0+h/3 of step s, stage 2 = t0+2h/3 of step s (s=0..T-2)
__global__ __launch_bounds__(256) void precompute_r(
    const float* __restrict__ u, const float* __restrict__ Wni,
    const float* __restrict__ bni, const float* __restrict__ Wli,
    const float* __restrict__ bli, const float* __restrict__ tau,
    float* __restrict__ r_out)
{
    __shared__ float sWni[NHI * NIN];
    __shared__ float sbni[NHI];
    __shared__ float sWli[NHI];
    int lt = threadIdx.x;
    for (int i = lt; i < NHI * NIN; i += 256) sWni[i] = Wni[i];
    if (lt < NHI) { sbni[lt] = bni[lt]; sWli[lt] = Wli[lt]; }
    __syncthreads();

    long long tid = (long long)blockIdx.x * 256 + lt;
    int s = (int)(tid % TT);
    int rbi = (int)(tid / TT);
    int b = rbi % BB;
    int stage = rbi / BB;
    if (stage > 0 && s >= TT - 1) return;  // interior stages only have T-1 steps

    const float DELTA = tg_delta();
    float ut[NIN];
    const float* up = u + ((long long)b * TT + s) * NIN;
    if (stage == 0) {
        #pragma unroll
        for (int k = 0; k < NIN; k++) ut[k] = up[k];
    } else {
        float t0 = (float)s * DELTA;
        float t1 = (float)(s + 1) * DELTA;
        float h = t1 - t0;
        float t = (stage == 1) ? (t0 + h / 3.0f) : (t0 + (2.0f * h) / 3.0f);
        float frac = (t - t0) / h;
        frac = fminf(fmaxf(frac, 0.0f), 1.0f);
        #pragma unroll
        for (int k = 0; k < NIN; k++) {
            float lo = up[k];
            float hi = up[NIN + k];
            ut[k] = lo + (hi - lo) * frac;
        }
    }

    float dparam = 0.0f;
    #pragma unroll 4
    for (int j = 0; j < NHI; j++) {
        float z = sbni[j];
        #pragma unroll
        for (int k = 0; k < NIN; k++) z += sWni[j * NIN + k] * ut[k];
        float sg = 1.0f / (1.0f + expf(-z));
        dparam += sWli[j] * sg;
    }
    dparam += bli[0];
    float e = expf(tau[0] + dparam);
    r_out[((long long)stage * BB + b) * TT + s] = 1.0f / e;
}

// ---------------- sequential RK4 (3/8 rule) scan ---------------------------
#define GFUN(a0, a1, a2, r, o0, o1, o2) do { \
    float t0_ = tanhf(a0); \
    float t1_ = tanhf(a1); \
    float t2_ = tanhf(a2); \
    o0 = ((-(a0)) + t1_) * (r); \
    o1 = ((-(a1)) + t2_) * (r); \
    o2 = (((-(a2)) + (-20.0f) * t0_) + 10.0f * t1_) * (r); \
} while (0)

__global__ __launch_bounds__(64) void scan_kernel(
    const float* __restrict__ r_all, float* __restrict__ xs)
{
    int b = blockIdx.x * 64 + threadIdx.x;
    const float* rg = r_all + (long long)b * TT;                  // stage 0
    const float* ra = r_all + ((long long)BB + b) * TT;           // stage 1
    const float* rc = r_all + ((long long)2 * BB + b) * TT;       // stage 2
    float* xp = xs + (long long)b * TT * 3;
    const float DELTA = tg_delta();

    float x0 = 0.4736f, x1 = 0.8745f, x2 = 1.8497f;
    xp[0] = x0; xp[1] = x1; xp[2] = x2;
    float rnext = rg[0];

    for (int s = 0; s < TT - 1; s++) {
        float r1 = rnext;
        float r2 = ra[s];
        float r3 = rc[s];
        float r4 = rg[s + 1];
        rnext = r4;
        float t0 = (float)s * DELTA;
        float t1v = (float)(s + 1) * DELTA;
        float h = t1v - t0;

        float k1a, k1b, k1c, k2a, k2b, k2c, k3a, k3b, k3c, k4a, k4b, k4c;
        GFUN(x0, x1, x2, r1, k1a, k1b, k1c);

        float a0 = x0 + (h * k1a) / 3.0f;
        float a1 = x1 + (h * k1b) / 3.0f;
        float a2 = x2 + (h * k1c) / 3.0f;
        GFUN(a0, a1, a2, r2, k2a, k2b, k2c);

        float b0 = x0 + h * (k2a - k1a / 3.0f);
        float b1 = x1 + h * (k2b - k1b / 3.0f);
        float b2 = x2 + h * (k2c - k1c / 3.0f);
        GFUN(b0, b1, b2, r3, k3a, k3b, k3c);

        float c0 = x0 + h * ((k1a - k2a) + k3a);
        float c1 = x1 + h * ((k1b - k2b) + k3b);
        float c2 = x2 + h * ((k1c - k2c) + k3c);
        GFUN(c0, c1, c2, r4, k4a, k4b, k4c);

        x0 = x0 + (h * (((k1a + 3.0f * k2a) + 3.0f * k3a) + k4a)) / 8.0f;
        x1 = x1 + (h * (((k1b + 3.0f * k2b) + 3.0f * k3b) + k4b)) / 8.0f;
        x2 = x2 + (h * (((k1c + 3.0f * k2c) + 3.0f * k3c) + k4c)) / 8.0f;

        float* w = xp + (long long)(s + 1) * 3;
        w[0] = x0; w[1] = x1; w[2] = x2;
    }
}

// ---------------- readout: out = sigmoid(x @ Wn^T + bn) @ Wl^T + bl --------
__global__ __launch_bounds__(256) void out_kernel(
    const float* __restrict__ xs, const float* __restrict__ Wn,
    const float* __restrict__ bn, const float* __restrict__ Wl,
    const float* __restrict__ bl, float* __restrict__ out)
{
    __shared__ float sWn[NHI * 3];
    __shared__ float sbn[NHI];
    __shared__ float sWl[NHI];
    int lt = threadIdx.x;
    if (lt < NHI * 3) sWn[lt] = Wn[lt];
    if (lt < NHI) { sbn[lt] = bn[lt]; sWl[lt] = Wl[lt]; }
    __syncthreads();

    long long tid = (long long)blockIdx.x * 256 + lt;  // tid = b*T + t
    const float* xpt = xs + tid * 3;
    float c0 = xpt[0], c1 = xpt[1], c2 = xpt[2];
    float acc = 0.0f;
    #pragma unroll 8
    for (int j = 0; j < NHI; j++) {
        float z = sbn[j] + sWn[j * 3] * c0 + sWn[j * 3 + 1] * c1 + sWn[j * 3 + 2] * c2;
        acc += sWl[j] * (1.0f / (1.0f + expf(-z)));
    }
    out[tid] = acc + bl[0];
}

extern "C" void kernel_launch(void* const* d_in, const int* in_sizes, int n_in,
                              void* d_out, int out_size, void* d_ws, size_t ws_size,
                              hipStream_t stream) {
    const float* u    = (const float*)d_in[0];
    const float* Wni  = (const float*)d_in[1];
    const float* bni  = (const float*)d_in[2];
    const float* Wli  = (const float*)d_in[3];
    const float* bli  = (const float*)d_in[4];
    const float* tau  = (const float*)d_in[5];
    const float* Wn   = (const float*)d_in[6];
    const float* bn   = (const float*)d_in[7];
    const float* Wl   = (const float*)d_in[8];
    const float* bl   = (const float*)d_in[9];
    float* out = (float*)d_out;

    float* r_all = (float*)d_ws;                       // 3*B*T floats
    float* xs    = r_all + (size_t)3 * BB * TT;        // 3*B*T floats

    long long total_pre = (long long)3 * BB * TT;
    precompute_r<<<(int)((total_pre + 255) / 256), 256, 0, stream>>>(
        u, Wni, bni, Wli, bli, tau, r_all);

    scan_kernel<<<BB / 64, 64, 0, stream>>>(r_all, xs);

    out_kernel<<<(BB * TT) / 256, 256, 0, stream>>>(xs, Wn, bn, Wl, bl, out);
}

// Round 2
// 866.678 us; speedup vs baseline: 2.9452x; 2.9452x over previous
//
#include <hip/hip_runtime.h>

#define BB 1024
#define TT 2048
#define NIN 8
#define NHI 64

__device__ __forceinline__ float tg_delta() { return 40.94f / 2047.0f; }

// fast tanh: tanh(x) = 1 - 2/(1 + exp2(2*log2e * x)), rcp + 1 Newton step
__device__ __forceinline__ float fast_tanh(float x) {
    float e = __builtin_amdgcn_exp2f(x * 2.8853900817779268f);
    float d = e + 1.0f;
    float r = __builtin_amdgcn_rcpf(d);
    r = fmaf(fmaf(-d, r, 1.0f), r, r);      // Newton refinement
    return fmaf(-2.0f, r, 1.0f);
}

// fast sigmoid: 1/(1+exp(-z)) = rcp(1 + exp2(-log2e * z))
__device__ __forceinline__ float fast_sigmoid(float z) {
    float e = __builtin_amdgcn_exp2f(z * -1.4426950408889634f);
    return __builtin_amdgcn_rcpf(1.0f + e);
}

// ---------------- precompute r = 1/exp(tau + dparam) for all eval points ----
// layout: r_out[stage][b][s]; stage 0 = grid point s, stages 1/2 = interior
__global__ __launch_bounds__(256) void precompute_r(
    const float* __restrict__ u, const float* __restrict__ Wni,
    const float* __restrict__ bni, const float* __restrict__ Wli,
    const float* __restrict__ bli, const float* __restrict__ tau,
    float* __restrict__ r_out)
{
    __shared__ float sWni[NHI * NIN];
    __shared__ float sbni[NHI];
    __shared__ float sWli[NHI];
    int lt = threadIdx.x;
    for (int i = lt; i < NHI * NIN; i += 256) sWni[i] = Wni[i];
    if (lt < NHI) { sbni[lt] = bni[lt]; sWli[lt] = Wli[lt]; }
    __syncthreads();

    long long tid = (long long)blockIdx.x * 256 + lt;
    int s = (int)(tid % TT);
    int rbi = (int)(tid / TT);
    int b = rbi % BB;
    int stage = rbi / BB;
    if (stage > 0 && s >= TT - 1) return;

    const float DELTA = tg_delta();
    float ut[NIN];
    const float4* up4 = reinterpret_cast<const float4*>(u + ((long long)b * TT + s) * NIN);
    float4 l0 = up4[0], l1 = up4[1];
    if (stage == 0) {
        ut[0] = l0.x; ut[1] = l0.y; ut[2] = l0.z; ut[3] = l0.w;
        ut[4] = l1.x; ut[5] = l1.y; ut[6] = l1.z; ut[7] = l1.w;
    } else {
        float4 h0 = up4[2], h1 = up4[3];
        float t0 = (float)s * DELTA;
        float t1 = (float)(s + 1) * DELTA;
        float h = t1 - t0;
        float t = (stage == 1) ? (t0 + h / 3.0f) : (t0 + (2.0f * h) / 3.0f);
        float frac = (t - t0) / h;
        frac = fminf(fmaxf(frac, 0.0f), 1.0f);
        float lo[NIN] = {l0.x, l0.y, l0.z, l0.w, l1.x, l1.y, l1.z, l1.w};
        float hi[NIN] = {h0.x, h0.y, h0.z, h0.w, h1.x, h1.y, h1.z, h1.w};
        #pragma unroll
        for (int k = 0; k < NIN; k++) ut[k] = lo[k] + (hi[k] - lo[k]) * frac;
    }

    float dparam = 0.0f;
    #pragma unroll 8
    for (int j = 0; j < NHI; j++) {
        float z = sbni[j];
        #pragma unroll
        for (int k = 0; k < NIN; k++) z += sWni[j * NIN + k] * ut[k];
        dparam += sWli[j] * fast_sigmoid(z);
    }
    dparam += bli[0];
    // r = exp(-(tau+dparam)) = exp2(-log2e*(tau+dparam))
    float r = __builtin_amdgcn_exp2f((tau[0] + dparam) * -1.4426950408889634f);
    r_out[((long long)stage * BB + b) * TT + s] = r;
}

// ---------------- sequential RK4 (3/8 rule) scan ---------------------------
__global__ __launch_bounds__(64) void scan_kernel(
    const float* __restrict__ r_all, float* __restrict__ xs)
{
    int b = blockIdx.x * 64 + threadIdx.x;
    const float* rg = r_all + (long long)b * TT;              // stage 0 (grid)
    const float* ra = r_all + ((long long)BB + b) * TT;       // stage 1 (h/3)
    const float* rc = r_all + ((long long)2 * BB + b) * TT;   // stage 2 (2h/3)
    float* xp = xs + (long long)b * TT * 3;
    const float DELTA = tg_delta();

    float x0 = 0.4736f, x1 = 0.8745f, x2 = 1.8497f;
    xp[0] = x0; xp[1] = x1; xp[2] = x2;

    float r1 = rg[0];
    float r2c = ra[0], r3c = rc[0], r4c = rg[1];

    for (int s = 0; s < TT - 1; s++) {
        // prefetch next iteration's r values (off critical path)
        int sn = (s + 1 < TT - 1) ? (s + 1) : (TT - 2);
        float r2n = ra[sn], r3n = rc[sn], r4n = rg[sn + 1];

        float t0v = (float)s * DELTA;
        float t1v = (float)(s + 1) * DELTA;
        float h = t1v - t0v;

        // off-path coefficient products
        float hr1 = h * r1;
        float hr2 = h * r2c;
        float hr3 = h * r3c;
        float p1  = hr1 * (1.0f / 3.0f);
        float hr1_8  = hr1 * 0.125f;
        float hr2_38 = hr2 * 0.375f;
        float hr3_38 = hr3 * 0.375f;
        float hr4_8  = (h * r4c) * 0.125f;

        // ---- stage 1
        float t0 = fast_tanh(x0), t1 = fast_tanh(x1), t2 = fast_tanh(x2);
        float w10 = t1 - x0;
        float w11 = t2 - x1;
        float w12 = fmaf(10.0f, t1, fmaf(-20.0f, t0, -x2));
        float a0 = fmaf(p1, w10, x0);
        float a1 = fmaf(p1, w11, x1);
        float a2 = fmaf(p1, w12, x2);
        // bases usable later (computed during stage-2 tanh latency)
        float q30 = fmaf(-p1, w10, x0);           // x - h*k1/3
        float q31 = fmaf(-p1, w11, x1);
        float q32 = fmaf(-p1, w12, x2);
        float u40 = fmaf(hr1, w10, x0);           // x + h*k1
        float u41 = fmaf(hr1, w11, x1);
        float u42 = fmaf(hr1, w12, x2);
        float ac0 = fmaf(hr1_8, w10, x0);         // x + (h/8)k1
        float ac1 = fmaf(hr1_8, w11, x1);
        float ac2 = fmaf(hr1_8, w12, x2);

        // ---- stage 2
        float s0 = fast_tanh(a0), s1 = fast_tanh(a1), s2 = fast_tanh(a2);
        float w20 = s1 - a0;
        float w21 = s2 - a1;
        float w22 = fmaf(10.0f, s1, fmaf(-20.0f, s0, -a2));
        float b0 = fmaf(hr2, w20, q30);
        float b1 = fmaf(hr2, w21, q31);
        float b2 = fmaf(hr2, w22, q32);
        float q40 = fmaf(-hr2, w20, u40);         // x + h*(k1-k2)
        float q41 = fmaf(-hr2, w21, u41);
        float q42 = fmaf(-hr2, w22, u42);
        ac0 = fmaf(hr2_38, w20, ac0);
        ac1 = fmaf(hr2_38, w21, ac1);
        ac2 = fmaf(hr2_38, w22, ac2);

        // ---- stage 3
        float v0 = fast_tanh(b0), v1 = fast_tanh(b1), v2 = fast_tanh(b2);
        float w30 = v1 - b0;
        float w31 = v2 - b1;
        float w32 = fmaf(10.0f, v1, fmaf(-20.0f, v0, -b2));
        float c0 = fmaf(hr3, w30, q40);
        float c1 = fmaf(hr3, w31, q41);
        float c2 = fmaf(hr3, w32, q42);
        ac0 = fmaf(hr3_38, w30, ac0);
        ac1 = fmaf(hr3_38, w31, ac1);
        ac2 = fmaf(hr3_38, w32, ac2);

        // ---- stage 4
        float y0 = fast_tanh(c0), y1 = fast_tanh(c1), y2 = fast_tanh(c2);
        float w40 = y1 - c0;
        float w41 = y2 - c1;
        float w42 = fmaf(10.0f, y1, fmaf(-20.0f, y0, -c2));
        x0 = fmaf(hr4_8, w40, ac0);
        x1 = fmaf(hr4_8, w41, ac1);
        x2 = fmaf(hr4_8, w42, ac2);

        float* w = xp + (long long)(s + 1) * 3;
        w[0] = x0; w[1] = x1; w[2] = x2;

        r1 = r4c; r2c = r2n; r3c = r3n; r4c = r4n;
    }
}

// ---------------- readout: out = sigmoid(x @ Wn^T + bn) @ Wl^T + bl --------
__global__ __launch_bounds__(256) void out_kernel(
    const float* __restrict__ xs, const float* __restrict__ Wn,
    const float* __restrict__ bn, const float* __restrict__ Wl,
    const float* __restrict__ bl, float* __restrict__ out)
{
    __shared__ float sWn[NHI * 3];
    __shared__ float sbn[NHI];
    __shared__ float sWl[NHI];
    int lt = threadIdx.x;
    if (lt < NHI * 3) sWn[lt] = Wn[lt];
    if (lt < NHI) { sbn[lt] = bn[lt]; sWl[lt] = Wl[lt]; }
    __syncthreads();

    long long tid = (long long)blockIdx.x * 256 + lt;  // tid = b*T + t
    const float* xpt = xs + tid * 3;
    float c0 = xpt[0], c1 = xpt[1], c2 = xpt[2];
    float acc = 0.0f;
    #pragma unroll 8
    for (int j = 0; j < NHI; j++) {
        float z = sbn[j] + sWn[j * 3] * c0 + sWn[j * 3 + 1] * c1 + sWn[j * 3 + 2] * c2;
        acc += sWl[j] * fast_sigmoid(z);
    }
    out[tid] = acc + bl[0];
}

extern "C" void kernel_launch(void* const* d_in, const int* in_sizes, int n_in,
                              void* d_out, int out_size, void* d_ws, size_t ws_size,
                              hipStream_t stream) {
    const float* u    = (const float*)d_in[0];
    const float* Wni  = (const float*)d_in[1];
    const float* bni  = (const float*)d_in[2];
    const float* Wli  = (const float*)d_in[3];
    const float* bli  = (const float*)d_in[4];
    const float* tau  = (const float*)d_in[5];
    const float* Wn   = (const float*)d_in[6];
    const float* bn   = (const float*)d_in[7];
    const float* Wl   = (const float*)d_in[8];
    const float* bl   = (const float*)d_in[9];
    float* out = (float*)d_out;

    float* r_all = (float*)d_ws;                       // 3*B*T floats
    float* xs    = r_all + (size_t)3 * BB * TT;        // 3*B*T floats

    long long total_pre = (long long)3 * BB * TT;
    precompute_r<<<(int)((total_pre + 255) / 256), 256, 0, stream>>>(
        u, Wni, bni, Wli, bli, tau, r_all);

    scan_kernel<<<BB / 64, 64, 0, stream>>>(r_all, xs);

    out_kernel<<<(BB * TT) / 256, 256, 0, stream>>>(xs, Wn, bn, Wl, bl, out);
}

// Round 3
// 583.733 us; speedup vs baseline: 4.3728x; 1.4847x over previous
//
#include <hip/hip_runtime.h>

#define BB 1024
#define TT 2048
#define NIN 8
#define NHI 64

#define CS 2.8853900817779268f      /* 2*log2(e) */
#define NL2E 1.4426950408889634f    /* log2(e) */
#define DELTA (40.94f / 2047.0f)

// sigmoid with pre-scaled input: zs = -log2e * z  ->  1/(1+exp2(zs))
__device__ __forceinline__ float sig_pre(float zs) {
    float e = __builtin_amdgcn_exp2f(zs);
    return __builtin_amdgcn_rcpf(1.0f + e);
}

// ---------------- precompute r records [b][s][{rg,ra,rc}] -------------------
// z = u@Wni.T is linear in u, so interior-stage z is interpolated from grid z.
// Each wave covers 64 consecutive grid points of one b, produces 63 steps'
// interior values (z[s+1] via shfl_down); waves overlap by 1 grid point.
__global__ __launch_bounds__(256) void precompute_r(
    const float* __restrict__ u, const float* __restrict__ Wni,
    const float* __restrict__ bni, const float* __restrict__ Wli,
    const float* __restrict__ bli, const float* __restrict__ tau,
    float* __restrict__ r3)
{
    __shared__ float sWni[NHI * NIN];
    __shared__ float sbni[NHI];
    __shared__ float sWli[NHI];
    int lt = threadIdx.x;
    for (int i = lt; i < NHI * NIN; i += 256) sWni[i] = Wni[i] * -NL2E;
    if (lt < NHI) { sbni[lt] = bni[lt] * -NL2E; sWli[lt] = Wli[lt]; }
    __syncthreads();

    int lane = lt & 63;
    long long gw = (long long)blockIdx.x * 4 + (lt >> 6);   // 1024*33 waves
    int b = (int)(gw / 33);
    int chunk = (int)(gw % 33);
    int s = chunk * 63 + lane;
    int sc = s < TT ? s : TT - 1;

    const float4* up4 = reinterpret_cast<const float4*>(u + ((long long)b * TT + sc) * NIN);
    float4 uA = up4[0], uB = up4[1];

    float d0 = 0.f, d1 = 0.f, d2 = 0.f;
    #pragma unroll 8
    for (int j = 0; j < NHI; j++) {
        const float* wj = &sWni[j * NIN];
        float z = sbni[j];
        z = fmaf(wj[0], uA.x, z); z = fmaf(wj[1], uA.y, z);
        z = fmaf(wj[2], uA.z, z); z = fmaf(wj[3], uA.w, z);
        z = fmaf(wj[4], uB.x, z); z = fmaf(wj[5], uB.y, z);
        z = fmaf(wj[6], uB.z, z); z = fmaf(wj[7], uB.w, z);
        float zn = __shfl_down(z, 1);
        float dz = zn - z;
        float z1 = fmaf(dz, 1.0f / 3.0f, z);
        float z2 = fmaf(dz, 2.0f / 3.0f, z);
        float wl = sWli[j];
        d0 = fmaf(wl, sig_pre(z),  d0);
        d1 = fmaf(wl, sig_pre(z1), d1);
        d2 = fmaf(wl, sig_pre(z2), d2);
    }
    float base = tau[0] + bli[0];
    float r0 = __builtin_amdgcn_exp2f((base + d0) * -NL2E);
    float r1 = __builtin_amdgcn_exp2f((base + d1) * -NL2E);
    float r2 = __builtin_amdgcn_exp2f((base + d2) * -NL2E);

    if (s < TT) {
        float* p = r3 + ((long long)b * TT + s) * 3;
        p[0] = r0;                                   // rg[s], incl. s = TT-1
        if (lane < 63 && s < TT - 1) { p[1] = r1; p[2] = r2; }
    }
}

// ---------------- sequential RK4 (3/8 rule) scan, scaled state --------------
// State X = CS*x. tanh(x) = 1 - 2*rcp(1 + exp2(X)). Per-stage critical path:
// exp2 -> add1 -> rcp -> fma(W) -> fma(next input)  (+1 fma for comp 2).
__global__ __launch_bounds__(64) void scan_kernel(
    const float* __restrict__ r3, float* __restrict__ xs)
{
    int b = blockIdx.x * 64 + threadIdx.x;
    const float4* rp = reinterpret_cast<const float4*>(r3 + (long long)b * TT * 3);
    float* xp = xs + (long long)b * TT * 3;

    const float h = DELTA;
    float X0 = 0.4736f * CS, X1 = 0.8745f * CS, X2 = 1.8497f * CS;
    xp[0] = 0.4736f; xp[1] = 0.8745f; xp[2] = 1.8497f;

#define STEP(sidx, R1v, R2v, R3v, R4v) do { \
    float hr1 = h * (R1v); \
    float hr2 = h * (R2v); \
    float hr3 = h * (R3v); \
    float p1 = hr1 * (1.0f / 3.0f); \
    float hr1_8 = hr1 * 0.125f; \
    float hr2_38 = hr2 * 0.375f; \
    float hr3_38 = hr3 * 0.375f; \
    float hr4_8 = (h * (R4v)) * 0.125f; \
    /* stage 1 */ \
    float C10 = CS - X0, C11 = CS - X1, K1 = fmaf(-10.0f, CS, -X2); \
    float Ra0 = __builtin_amdgcn_rcpf(1.0f + __builtin_amdgcn_exp2f(X0)); \
    float Ra1 = __builtin_amdgcn_rcpf(1.0f + __builtin_amdgcn_exp2f(X1)); \
    float Ra2 = __builtin_amdgcn_rcpf(1.0f + __builtin_amdgcn_exp2f(X2)); \
    float W10 = fmaf(-2.0f * CS, Ra1, C10); \
    float W11 = fmaf(-2.0f * CS, Ra2, C11); \
    float W12 = fmaf(40.0f * CS, Ra0, fmaf(-20.0f * CS, Ra1, K1)); \
    float A0 = fmaf(p1, W10, X0), A1 = fmaf(p1, W11, X1), A2 = fmaf(p1, W12, X2); \
    float Q30 = fmaf(-p1, W10, X0), Q31 = fmaf(-p1, W11, X1), Q32 = fmaf(-p1, W12, X2); \
    float U40 = fmaf(hr1, W10, X0), U41 = fmaf(hr1, W11, X1), U42 = fmaf(hr1, W12, X2); \
    float AC0 = fmaf(hr1_8, W10, X0), AC1 = fmaf(hr1_8, W11, X1), AC2 = fmaf(hr1_8, W12, X2); \
    /* stage 2 */ \
    float C20 = CS - A0, C21 = CS - A1, K2 = fmaf(-10.0f, CS, -A2); \
    float Rb0 = __builtin_amdgcn_rcpf(1.0f + __builtin_amdgcn_exp2f(A0)); \
    float Rb1 = __builtin_amdgcn_rcpf(1.0f + __builtin_amdgcn_exp2f(A1)); \
    float Rb2 = __builtin_amdgcn_rcpf(1.0f + __builtin_amdgcn_exp2f(A2)); \
    float W20 = fmaf(-2.0f * CS, Rb1, C20); \
    float W21 = fmaf(-2.0f * CS, Rb2, C21); \
    float W22 = fmaf(40.0f * CS, Rb0, fmaf(-20.0f * CS, Rb1, K2)); \
    float B0 = fmaf(hr2, W20, Q30), B1 = fmaf(hr2, W21, Q31), B2 = fmaf(hr2, W22, Q32); \
    float Q40 = fmaf(-hr2, W20, U40), Q41 = fmaf(-hr2, W21, U41), Q42 = fmaf(-hr2, W22, U42); \
    AC0 = fmaf(hr2_38, W20, AC0); AC1 = fmaf(hr2_38, W21, AC1); AC2 = fmaf(hr2_38, W22, AC2); \
    /* stage 3 */ \
    float C30 = CS - B0, C31 = CS - B1, K3 = fmaf(-10.0f, CS, -B2); \
    float Rc0 = __builtin_amdgcn_rcpf(1.0f + __builtin_amdgcn_exp2f(B0)); \
    float Rc1 = __builtin_amdgcn_rcpf(1.0f + __builtin_amdgcn_exp2f(B1)); \
    float Rc2 = __builtin_amdgcn_rcpf(1.0f + __builtin_amdgcn_exp2f(B2)); \
    float W30 = fmaf(-2.0f * CS, Rc1, C30); \
    float W31 = fmaf(-2.0f * CS, Rc2, C31); \
    float W32 = fmaf(40.0f * CS, Rc0, fmaf(-20.0f * CS, Rc1, K3)); \
    float Cv0 = fmaf(hr3, W30, Q40), Cv1 = fmaf(hr3, W31, Q41), Cv2 = fmaf(hr3, W32, Q42); \
    AC0 = fmaf(hr3_38, W30, AC0); AC1 = fmaf(hr3_38, W31, AC1); AC2 = fmaf(hr3_38, W32, AC2); \
    /* stage 4 */ \
    float C40 = CS - Cv0, C41 = CS - Cv1, K4 = fmaf(-10.0f, CS, -Cv2); \
    float Rd0 = __builtin_amdgcn_rcpf(1.0f + __builtin_amdgcn_exp2f(Cv0)); \
    float Rd1 = __builtin_amdgcn_rcpf(1.0f + __builtin_amdgcn_exp2f(Cv1)); \
    float Rd2 = __builtin_amdgcn_rcpf(1.0f + __builtin_amdgcn_exp2f(Cv2)); \
    float W40 = fmaf(-2.0f * CS, Rd1, C40); \
    float W41 = fmaf(-2.0f * CS, Rd2, C41); \
    float W42 = fmaf(40.0f * CS, Rd0, fmaf(-20.0f * CS, Rd1, K4)); \
    X0 = fmaf(hr4_8, W40, AC0); \
    X1 = fmaf(hr4_8, W41, AC1); \
    X2 = fmaf(hr4_8, W42, AC2); \
    float* wp_ = xp + (long long)((sidx) + 1) * 3; \
    wp_[0] = X0 * (1.0f / CS); wp_[1] = X1 * (1.0f / CS); wp_[2] = X2 * (1.0f / CS); \
} while (0)

    // chunk c covers steps 4c..4c+3; flat12 = {rg,ra,rc} of records 4c..4c+3.
    // step 4c+k: r1=flat[3k], r2=flat[3k+1], r3=flat[3k+2], r4=flat[3k+3].
    float4 f0 = rp[0], f1 = rp[1], f2 = rp[2];        // chunk 0
    float4 n0 = rp[3], n1 = rp[4], n2 = rp[5];        // chunk 1

    for (int j = 0; j < 510; j++) {                    // chunks 0..509
        float4 m0 = rp[3 * j + 6], m1 = rp[3 * j + 7], m2 = rp[3 * j + 8];
        int s4 = 4 * j;
        STEP(s4 + 0, f0.x, f0.y, f0.z, f0.w);
        STEP(s4 + 1, f0.w, f1.x, f1.y, f1.z);
        STEP(s4 + 2, f1.z, f1.w, f2.x, f2.y);
        STEP(s4 + 3, f2.y, f2.z, f2.w, n0.x);
        f0 = n0; f1 = n1; f2 = n2;
        n0 = m0; n1 = m1; n2 = m2;
    }
    // chunk 510 (steps 2040..2043), no further prefetch
    STEP(2040, f0.x, f0.y, f0.z, f0.w);
    STEP(2041, f0.w, f1.x, f1.y, f1.z);
    STEP(2042, f1.z, f1.w, f2.x, f2.y);
    STEP(2043, f2.y, f2.z, f2.w, n0.x);
    f0 = n0; f1 = n1; f2 = n2;
    // tail: steps 2044..2046 (chunk 511; record 2047 field 0 = rg[2047] valid)
    STEP(2044, f0.x, f0.y, f0.z, f0.w);
    STEP(2045, f0.w, f1.x, f1.y, f1.z);
    STEP(2046, f1.z, f1.w, f2.x, f2.y);
#undef STEP
}

// ---------------- readout: out = sigmoid(x @ Wn^T + bn) @ Wl^T + bl --------
__global__ __launch_bounds__(256) void out_kernel(
    const float* __restrict__ xs, const float* __restrict__ Wn,
    const float* __restrict__ bn, const float* __restrict__ Wl,
    const float* __restrict__ bl, float* __restrict__ out)
{
    __shared__ float sWn[NHI * 3];
    __shared__ float sbn[NHI];
    __shared__ float sWl[NHI];
    int lt = threadIdx.x;
    if (lt < NHI * 3) sWn[lt] = Wn[lt] * -NL2E;
    if (lt < NHI) { sbn[lt] = bn[lt] * -NL2E; sWl[lt] = Wl[lt]; }
    __syncthreads();

    long long tid = (long long)blockIdx.x * 256 + lt;   // tid = b*T + t
    const float* xpt = xs + tid * 3;
    float c0 = xpt[0], c1 = xpt[1], c2 = xpt[2];
    float acc = 0.0f;
    #pragma unroll 8
    for (int j = 0; j < NHI; j++) {
        float z = fmaf(sWn[j * 3], c0,
                  fmaf(sWn[j * 3 + 1], c1,
                  fmaf(sWn[j * 3 + 2], c2, sbn[j])));
        acc = fmaf(sWl[j], sig_pre(z), acc);
    }
    out[tid] = acc + bl[0];
}

extern "C" void kernel_launch(void* const* d_in, const int* in_sizes, int n_in,
                              void* d_out, int out_size, void* d_ws, size_t ws_size,
                              hipStream_t stream) {
    const float* u    = (const float*)d_in[0];
    const float* Wni  = (const float*)d_in[1];
    const float* bni  = (const float*)d_in[2];
    const float* Wli  = (const float*)d_in[3];
    const float* bli  = (const float*)d_in[4];
    const float* tau  = (const float*)d_in[5];
    const float* Wn   = (const float*)d_in[6];
    const float* bn   = (const float*)d_in[7];
    const float* Wl   = (const float*)d_in[8];
    const float* bl   = (const float*)d_in[9];
    float* out = (float*)d_out;

    float* r3 = (float*)d_ws;                          // B*T*3 floats (24 MB)
    float* xs = r3 + (size_t)3 * BB * TT;              // B*T*3 floats (24 MB)

    precompute_r<<<(BB * 33) / 4, 256, 0, stream>>>(u, Wni, bni, Wli, bli, tau, r3);
    scan_kernel<<<BB / 64, 64, 0, stream>>>(r3, xs);
    out_kernel<<<(BB * TT) / 256, 256, 0, stream>>>(xs, Wn, bn, Wl, bl, out);
}

// Round 4
// 455.658 us; speedup vs baseline: 5.6019x; 1.2811x over previous
//
#include <hip/hip_runtime.h>

#define BB 1024
#define TT 2048
#define NIN 8
#define NHI 64

#define CS 2.8853900817779268f      /* 2*log2(e) */
#define NL2E 1.4426950408889634f    /* log2(e) */
#define DELTA (40.94f / 2047.0f)

// sigmoid with pre-scaled input: zs = -log2e * z  ->  1/(1+exp2(zs))
__device__ __forceinline__ float sig_pre(float zs) {
    float e = __builtin_amdgcn_exp2f(zs);
    return __builtin_amdgcn_rcpf(1.0f + e);
}

template<int CTRL>
__device__ __forceinline__ float qperm(float x) {
    int r = __builtin_amdgcn_mov_dpp(__float_as_int(x), CTRL, 0xF, 0xF, true);
    return __int_as_float(r);
}

// ---------------- precompute r records [b][s][{rg,ra,rc}] -------------------
__global__ __launch_bounds__(256) void precompute_r(
    const float* __restrict__ u, const float* __restrict__ Wni,
    const float* __restrict__ bni, const float* __restrict__ Wli,
    const float* __restrict__ bli, const float* __restrict__ tau,
    float* __restrict__ r3)
{
    __shared__ float sWni[NHI * NIN];
    __shared__ float sbni[NHI];
    __shared__ float sWli[NHI];
    int lt = threadIdx.x;
    for (int i = lt; i < NHI * NIN; i += 256) sWni[i] = Wni[i] * -NL2E;
    if (lt < NHI) { sbni[lt] = bni[lt] * -NL2E; sWli[lt] = Wli[lt]; }
    __syncthreads();

    int lane = lt & 63;
    long long gw = (long long)blockIdx.x * 4 + (lt >> 6);   // 1024*33 waves
    int b = (int)(gw / 33);
    int chunk = (int)(gw % 33);
    int s = chunk * 63 + lane;
    int sc = s < TT ? s : TT - 1;

    const float4* up4 = reinterpret_cast<const float4*>(u + ((long long)b * TT + sc) * NIN);
    float4 uA = up4[0], uB = up4[1];

    float d0 = 0.f, d1 = 0.f, d2 = 0.f;
    #pragma unroll 8
    for (int j = 0; j < NHI; j++) {
        const float* wj = &sWni[j * NIN];
        float z = sbni[j];
        z = fmaf(wj[0], uA.x, z); z = fmaf(wj[1], uA.y, z);
        z = fmaf(wj[2], uA.z, z); z = fmaf(wj[3], uA.w, z);
        z = fmaf(wj[4], uB.x, z); z = fmaf(wj[5], uB.y, z);
        z = fmaf(wj[6], uB.z, z); z = fmaf(wj[7], uB.w, z);
        float zn = __shfl_down(z, 1);
        float dz = zn - z;
        float z1 = fmaf(dz, 1.0f / 3.0f, z);
        float z2 = fmaf(dz, 2.0f / 3.0f, z);
        float wl = sWli[j];
        d0 = fmaf(wl, sig_pre(z),  d0);
        d1 = fmaf(wl, sig_pre(z1), d1);
        d2 = fmaf(wl, sig_pre(z2), d2);
    }
    float base = tau[0] + bli[0];
    float r0 = __builtin_amdgcn_exp2f((base + d0) * -NL2E);
    float r1 = __builtin_amdgcn_exp2f((base + d1) * -NL2E);
    float r2 = __builtin_amdgcn_exp2f((base + d2) * -NL2E);

    if (s < TT) {
        float* p = r3 + ((long long)b * TT + s) * 3;
        p[0] = r0;
        if (lane < 63 && s < TT - 1) { p[1] = r1; p[2] = r2; }
    }
}

// ---------------- sequential RK4 scan: one b per quad, lane = component -----
// Scaled state X = CS*x; tanh(x) = 1 - 2*rcp(1+exp2(X)).
// lane0: comp0, lane1: comp1, lane2: comp2, lane3: mirrors comp1 (so its
// rcp == r1, keeping all quad lanes finite & uniform).
// perm1 ctrl 0x89 = sel[1,2,0,2]: each lane pulls its primary neighbor r.
// perm2 ctrl 0x10 = sel[0,0,1,0]: lane2 pulls r1 (others unused, cB=0).
__global__ __launch_bounds__(64) void scan_kernel(
    const float* __restrict__ r3, float* __restrict__ xs)
{
    int gt = blockIdx.x * 64 + threadIdx.x;     // 4096 threads
    int b = gt >> 2;
    int l = gt & 3;

    const float4* rp = reinterpret_cast<const float4*>(r3 + (long long)b * TT * 3);
    float* xp3 = xs + (long long)b * TT * 3;

    const float h = DELTA;
    bool is2 = (l == 2);
    float cA = is2 ? 40.0f * CS : -2.0f * CS;   // coeff of perm1 value
    float cB = is2 ? -20.0f * CS : 0.0f;        // coeff of perm2 value
    float Kl = is2 ? -10.0f * CS : CS;          // W = cA*p1v + cB*p2v + (Kl - X)

    float X = (l == 0) ? 0.4736f * CS : (is2 ? 1.8497f * CS : 0.8745f * CS);
    if (l < 3) xp3[l] = X * (1.0f / CS);

#define QSTAGE(Xin, Wout) \
    { float e_ = __builtin_amdgcn_exp2f(Xin); \
      float r_ = __builtin_amdgcn_rcpf(1.0f + e_); \
      float p1_ = qperm<0x89>(r_); \
      float p2_ = qperm<0x10>(r_); \
      Wout = fmaf(cA, p1_, fmaf(cB, p2_, Kl - (Xin))); }

#define STEP(sidx, R1v, R2v, R3v, R4v) do { \
    float hr1 = h * (R1v), hr2 = h * (R2v), hr3 = h * (R3v); \
    float q1 = hr1 * (1.0f / 3.0f); \
    float a1 = hr1 * 0.125f, a2 = hr2 * 0.375f, a3 = hr3 * 0.375f; \
    float hr4_8 = (h * (R4v)) * 0.125f; \
    float W1, W2, W3, W4; \
    QSTAGE(X, W1); \
    float A  = fmaf(q1, W1, X); \
    float AC = fmaf(a1, W1, X); \
    float Q3 = fmaf(-q1, W1, X); \
    float U4 = fmaf(hr1, W1, X); \
    QSTAGE(A, W2); \
    float Bv = fmaf(hr2, W2, Q3); \
    float Q4 = fmaf(-hr2, W2, U4); \
    AC = fmaf(a2, W2, AC); \
    QSTAGE(Bv, W3); \
    float Cv = fmaf(hr3, W3, Q4); \
    AC = fmaf(a3, W3, AC); \
    QSTAGE(Cv, W4); \
    X = fmaf(hr4_8, W4, AC); \
    if (l < 3) xp3[(long long)((sidx) + 1) * 3 + l] = X * (1.0f / CS); \
} while (0)

    // chunk c covers steps 4c..4c+3; records {rg,ra,rc} of 4c..4c+3 = 3 float4
    float4 f0 = rp[0], f1 = rp[1], f2 = rp[2];
    float4 n0 = rp[3], n1 = rp[4], n2 = rp[5];

    for (int j = 0; j < 510; j++) {
        float4 m0 = rp[3 * j + 6], m1 = rp[3 * j + 7], m2 = rp[3 * j + 8];
        int s4 = 4 * j;
        STEP(s4 + 0, f0.x, f0.y, f0.z, f0.w);
        STEP(s4 + 1, f0.w, f1.x, f1.y, f1.z);
        STEP(s4 + 2, f1.z, f1.w, f2.x, f2.y);
        STEP(s4 + 3, f2.y, f2.z, f2.w, n0.x);
        f0 = n0; f1 = n1; f2 = n2;
        n0 = m0; n1 = m1; n2 = m2;
    }
    STEP(2040, f0.x, f0.y, f0.z, f0.w);
    STEP(2041, f0.w, f1.x, f1.y, f1.z);
    STEP(2042, f1.z, f1.w, f2.x, f2.y);
    STEP(2043, f2.y, f2.z, f2.w, n0.x);
    f0 = n0; f1 = n1; f2 = n2;
    STEP(2044, f0.x, f0.y, f0.z, f0.w);
    STEP(2045, f0.w, f1.x, f1.y, f1.z);
    STEP(2046, f1.z, f1.w, f2.x, f2.y);
#undef STEP
#undef QSTAGE
}

// ---------------- readout: out = sigmoid(x @ Wn^T + bn) @ Wl^T + bl --------
__global__ __launch_bounds__(256) void out_kernel(
    const float* __restrict__ xs, const float* __restrict__ Wn,
    const float* __restrict__ bn, const float* __restrict__ Wl,
    const float* __restrict__ bl, float* __restrict__ out)
{
    __shared__ float sWn[NHI * 3];
    __shared__ float sbn[NHI];
    __shared__ float sWl[NHI];
    int lt = threadIdx.x;
    if (lt < NHI * 3) sWn[lt] = Wn[lt] * -NL2E;
    if (lt < NHI) { sbn[lt] = bn[lt] * -NL2E; sWl[lt] = Wl[lt]; }
    __syncthreads();

    long long tid = (long long)blockIdx.x * 256 + lt;   // tid = b*T + t
    const float* xpt = xs + tid * 3;
    float c0 = xpt[0], c1 = xpt[1], c2 = xpt[2];
    float acc = 0.0f;
    #pragma unroll 8
    for (int j = 0; j < NHI; j++) {
        float z = fmaf(sWn[j * 3], c0,
                  fmaf(sWn[j * 3 + 1], c1,
                  fmaf(sWn[j * 3 + 2], c2, sbn[j])));
        acc = fmaf(sWl[j], sig_pre(z), acc);
    }
    out[tid] = acc + bl[0];
}

extern "C" void kernel_launch(void* const* d_in, const int* in_sizes, int n_in,
                              void* d_out, int out_size, void* d_ws, size_t ws_size,
                              hipStream_t stream) {
    const float* u    = (const float*)d_in[0];
    const float* Wni  = (const float*)d_in[1];
    const float* bni  = (const float*)d_in[2];
    const float* Wli  = (const float*)d_in[3];
    const float* bli  = (const float*)d_in[4];
    const float* tau  = (const float*)d_in[5];
    const float* Wn   = (const float*)d_in[6];
    const float* bn   = (const float*)d_in[7];
    const float* Wl   = (const float*)d_in[8];
    const float* bl   = (const float*)d_in[9];
    float* out = (float*)d_out;

    float* r3 = (float*)d_ws;                          // B*T*3 floats (24 MB)
    float* xs = r3 + (size_t)3 * BB * TT;              // B*T*3 floats (24 MB)

    precompute_r<<<(BB * 33) / 4, 256, 0, stream>>>(u, Wni, bni, Wli, bli, tau, r3);
    scan_kernel<<<(BB * 4) / 64, 64, 0, stream>>>(r3, xs);
    out_kernel<<<(BB * TT) / 256, 256, 0, stream>>>(xs, Wn, bn, Wl, bl, out);
}

// Round 5
// 437.850 us; speedup vs baseline: 5.8297x; 1.0407x over previous
//
#include <hip/hip_runtime.h>

#define BB 1024
#define TT 2048
#define NIN 8
#define NHI 64

#define CS 2.8853900817779268f      /* 2*log2(e) */
#define ICS (1.0f / CS)
#define NL2E 1.4426950408889634f    /* log2(e) */
#define DELTA (40.94f / 2047.0f)

__device__ __forceinline__ float sig_pre(float zs) {
    float e = __builtin_amdgcn_exp2f(zs);
    return __builtin_amdgcn_rcpf(1.0f + e);
}

template<int CTRL>
__device__ __forceinline__ float qperm(float x) {
    int r = __builtin_amdgcn_mov_dpp(__float_as_int(x), CTRL, 0xF, 0xF, true);
    return __int_as_float(r);
}

// ---------------- precompute r records [b][s][{rg,ra,rc}] -------------------
__global__ __launch_bounds__(256) void precompute_r(
    const float* __restrict__ u, const float* __restrict__ Wni,
    const float* __restrict__ bni, const float* __restrict__ Wli,
    const float* __restrict__ bli, const float* __restrict__ tau,
    float* __restrict__ r3)
{
    __shared__ float sWni[NHI * NIN];
    __shared__ float sbni[NHI];
    __shared__ float sWli[NHI];
    int lt = threadIdx.x;
    for (int i = lt; i < NHI * NIN; i += 256) sWni[i] = Wni[i] * -NL2E;
    if (lt < NHI) { sbni[lt] = bni[lt] * -NL2E; sWli[lt] = Wli[lt]; }
    __syncthreads();

    int lane = lt & 63;
    long long gw = (long long)blockIdx.x * 4 + (lt >> 6);   // 1024*33 waves
    int b = (int)(gw / 33);
    int chunk = (int)(gw % 33);
    int s = chunk * 63 + lane;
    int sc = s < TT ? s : TT - 1;

    const float4* up4 = reinterpret_cast<const float4*>(u + ((long long)b * TT + sc) * NIN);
    float4 uA = up4[0], uB = up4[1];

    float d0 = 0.f, d1 = 0.f, d2 = 0.f;
    #pragma unroll 8
    for (int j = 0; j < NHI; j++) {
        const float* wj = &sWni[j * NIN];
        float z = sbni[j];
        z = fmaf(wj[0], uA.x, z); z = fmaf(wj[1], uA.y, z);
        z = fmaf(wj[2], uA.z, z); z = fmaf(wj[3], uA.w, z);
        z = fmaf(wj[4], uB.x, z); z = fmaf(wj[5], uB.y, z);
        z = fmaf(wj[6], uB.z, z); z = fmaf(wj[7], uB.w, z);
        float zn = __shfl_down(z, 1);
        float dz = zn - z;
        float z1 = fmaf(dz, 1.0f / 3.0f, z);
        float z2 = fmaf(dz, 2.0f / 3.0f, z);
        float wl = sWli[j];
        d0 = fmaf(wl, sig_pre(z),  d0);
        d1 = fmaf(wl, sig_pre(z1), d1);
        d2 = fmaf(wl, sig_pre(z2), d2);
    }
    float base = tau[0] + bli[0];
    float r0 = __builtin_amdgcn_exp2f((base + d0) * -NL2E);
    float r1 = __builtin_amdgcn_exp2f((base + d1) * -NL2E);
    float r2 = __builtin_amdgcn_exp2f((base + d2) * -NL2E);

    if (s < TT) {
        float* p = r3 + ((long long)b * TT + s) * 3;
        p[0] = r0;
        if (lane < 63 && s < TT - 1) { p[1] = r1; p[2] = r2; }
    }
}

// ---------------- sequential RK4 scan: one b per quad, lane = component -----
// Scaled state X = CS*x. Per stage the dependent chain is exactly:
// exp2(S) -> 1+e -> rcp -> mov_dpp -> fma -> fma -> next S.
// All stage-combine algebra is folded into "prebases" computed off-chain.
// lane0..2 = components, lane3 mirrors comp1 (bit-identical).
__global__ __launch_bounds__(64) void scan_kernel(
    const float* __restrict__ r3, float* __restrict__ xs)
{
    int gt = blockIdx.x * 64 + threadIdx.x;     // 4096 threads
    int b = gt >> 2;
    int l = gt & 3;

    const float4* rp = reinterpret_cast<const float4*>(r3 + (long long)b * TT * 3);
    int comp = (l == 3) ? 1 : l;
    float* xc = xs + (long long)comp * BB * TT + (long long)b * TT;

    const float h = DELTA;
    bool is2 = (l == 2);
    float cA = is2 ? 40.0f * CS : -2.0f * CS;
    float cB = is2 ? -20.0f * CS : 0.0f;
    float Kl = is2 ? -10.0f * CS : CS;

    float X = (l == 0) ? 0.4736f * CS : (is2 ? 1.8497f * CS : 0.8745f * CS);

#define STEP(R1v, R2v, R3v, R4v) do { \
    float g1 = h * (R1v), g2 = h * (R2v), g3 = h * (R3v); \
    float q  = g1 * (1.0f / 3.0f); \
    float g4_8 = (h * (R4v)) * 0.125f; \
    float cA1 = q * cA,    cB1 = q * cB; \
    float cA2 = g2 * cA,   cB2 = g2 * cB; \
    float cA3 = g3 * cA,   cB3 = g3 * cB; \
    float cA4 = g4_8 * cA, cB4 = g4_8 * cB; \
    /* stage 1 */ \
    float e1 = __builtin_amdgcn_exp2f(X); \
    float rho1 = __builtin_amdgcn_rcpf(1.0f + e1); \
    float KmX = Kl - X; \
    float pb2 = fmaf(q, KmX, X); \
    float p11 = qperm<0x89>(rho1), p21 = qperm<0x10>(rho1); \
    float S2 = fmaf(cA1, p11, fmaf(cB1, p21, pb2)); \
    float V1 = fmaf(cA, p11, cB * p21); \
    float W1 = V1 + KmX; \
    /* stage 2 */ \
    float e2 = __builtin_amdgcn_exp2f(S2); \
    float rho2 = __builtin_amdgcn_rcpf(1.0f + e2); \
    float KmS2 = Kl - S2; \
    float pb3 = fmaf(g2, KmS2, fmaf(-q, W1, X)); \
    float p12 = qperm<0x89>(rho2), p22 = qperm<0x10>(rho2); \
    float S3 = fmaf(cA2, p12, fmaf(cB2, p22, pb3)); \
    float V2 = fmaf(cA, p12, cB * p22); \
    float W2 = V2 + KmS2; \
    /* stage 3 */ \
    float e3 = __builtin_amdgcn_exp2f(S3); \
    float rho3 = __builtin_amdgcn_rcpf(1.0f + e3); \
    float KmS3 = Kl - S3; \
    float pb4 = fmaf(g3, KmS3, fmaf(-g2, W2, fmaf(g1, W1, X))); \
    float p13 = qperm<0x89>(rho3), p23 = qperm<0x10>(rho3); \
    float S4 = fmaf(cA3, p13, fmaf(cB3, p23, pb4)); \
    float V3 = fmaf(cA, p13, cB * p23); \
    float W3 = V3 + KmS3; \
    /* stage 4 */ \
    float e4 = __builtin_amdgcn_exp2f(S4); \
    float rho4 = __builtin_amdgcn_rcpf(1.0f + e4); \
    float KmS4 = Kl - S4; \
    float t3 = fmaf(3.0f * g3, W3, fmaf(3.0f * g2, W2, g1 * W1)); \
    float pbX = fmaf(g4_8, KmS4, fmaf(0.125f, t3, X)); \
    float p14 = qperm<0x89>(rho4), p24 = qperm<0x10>(rho4); \
    X = fmaf(cA4, p14, fmaf(cB4, p24, pbX)); \
} while (0)

    // chunk j covers steps 4j..4j+3; pack holds X(4j..4j+3), stored aligned.
    float4 f0 = rp[0], f1 = rp[1], f2 = rp[2];
    float4 n0 = rp[3], n1 = rp[4], n2 = rp[5];

    for (int j = 0; j < 510; j++) {
        float4 m0 = rp[3 * j + 6], m1 = rp[3 * j + 7], m2 = rp[3 * j + 8];
        float4 ov;
        ov.x = X * ICS;
        STEP(f0.x, f0.y, f0.z, f0.w);  ov.y = X * ICS;
        STEP(f0.w, f1.x, f1.y, f1.z);  ov.z = X * ICS;
        STEP(f1.z, f1.w, f2.x, f2.y);  ov.w = X * ICS;
        *reinterpret_cast<float4*>(xc + 4 * j) = ov;
        STEP(f2.y, f2.z, f2.w, n0.x);
        f0 = n0; f1 = n1; f2 = n2;
        n0 = m0; n1 = m1; n2 = m2;
    }
    {   // chunk 510 (steps 2040..2043)
        float4 ov;
        ov.x = X * ICS;
        STEP(f0.x, f0.y, f0.z, f0.w);  ov.y = X * ICS;
        STEP(f0.w, f1.x, f1.y, f1.z);  ov.z = X * ICS;
        STEP(f1.z, f1.w, f2.x, f2.y);  ov.w = X * ICS;
        *reinterpret_cast<float4*>(xc + 4 * 510) = ov;
        STEP(f2.y, f2.z, f2.w, n0.x);
        f0 = n0; f1 = n1; f2 = n2;
    }
    {   // chunk 511 (steps 2044..2046, 3 steps -> X(2045..2047))
        float4 ov;
        ov.x = X * ICS;
        STEP(f0.x, f0.y, f0.z, f0.w);  ov.y = X * ICS;
        STEP(f0.w, f1.x, f1.y, f1.z);  ov.z = X * ICS;
        STEP(f1.z, f1.w, f2.x, f2.y);  ov.w = X * ICS;
        *reinterpret_cast<float4*>(xc + 4 * 511) = ov;
    }
#undef STEP
}

// ---------------- readout: out = sigmoid(x @ Wn^T + bn) @ Wl^T + bl --------
__global__ __launch_bounds__(256) void out_kernel(
    const float* __restrict__ xs, const float* __restrict__ Wn,
    const float* __restrict__ bn, const float* __restrict__ Wl,
    const float* __restrict__ bl, float* __restrict__ out)
{
    __shared__ float sWn[NHI * 3];
    __shared__ float sbn[NHI];
    __shared__ float sWl[NHI];
    int lt = threadIdx.x;
    if (lt < NHI * 3) sWn[lt] = Wn[lt] * -NL2E;
    if (lt < NHI) { sbn[lt] = bn[lt] * -NL2E; sWl[lt] = Wl[lt]; }
    __syncthreads();

    long long tid = (long long)blockIdx.x * 256 + lt;   // tid = b*T + t
    float c0 = xs[tid];
    float c1 = xs[(long long)BB * TT + tid];
    float c2 = xs[(long long)2 * BB * TT + tid];
    float acc = 0.0f;
    #pragma unroll 8
    for (int j = 0; j < NHI; j++) {
        float z = fmaf(sWn[j * 3], c0,
                  fmaf(sWn[j * 3 + 1], c1,
                  fmaf(sWn[j * 3 + 2], c2, sbn[j])));
        acc = fmaf(sWl[j], sig_pre(z), acc);
    }
    out[tid] = acc + bl[0];
}

extern "C" void kernel_launch(void* const* d_in, const int* in_sizes, int n_in,
                              void* d_out, int out_size, void* d_ws, size_t ws_size,
                              hipStream_t stream) {
    const float* u    = (const float*)d_in[0];
    const float* Wni  = (const float*)d_in[1];
    const float* bni  = (const float*)d_in[2];
    const float* Wli  = (const float*)d_in[3];
    const float* bli  = (const float*)d_in[4];
    const float* tau  = (const float*)d_in[5];
    const float* Wn   = (const float*)d_in[6];
    const float* bn   = (const float*)d_in[7];
    const float* Wl   = (const float*)d_in[8];
    const float* bl   = (const float*)d_in[9];
    float* out = (float*)d_out;

    float* r3 = (float*)d_ws;                          // B*T*3 floats (24 MB)
    float* xs = r3 + (size_t)3 * BB * TT;              // [3][B][T] (24 MB)

    precompute_r<<<(BB * 33) / 4, 256, 0, stream>>>(u, Wni, bni, Wli, bli, tau, r3);
    scan_kernel<<<(BB * 4) / 64, 64, 0, stream>>>(r3, xs);
    out_kernel<<<(BB * TT) / 256, 256, 0, stream>>>(xs, Wn, bn, Wl, bl, out);
}